// Round 12
// baseline (200.006 us; speedup 1.0000x reference)
//
#include <hip/hip_runtime.h>
#include <hip/hip_bf16.h>

// LocallyConnected2d: x(32,48,64,64) f32, weight(48,64,64,48,3,3) f32, bias(48) f32
// out(32,48,64,64) f32.  Per-location GEMM M=32(b) x N=48(o) x K=432, bf16 MFMA.
//
// R12: OPERAND SWAP in main. mfma(A=weights, B=x_unf):
//  - A (weights) global->reg per-lane contiguous 32B chunks, no LDS, no glds
//    convoy; 12 independent streaming waves/CU.
//  - B (unf tile) staged ONCE per block in LDS (2l x 32b x 448k bf16, pitch
//    456, 2-way-conflict-free); block covers all 48 o (6 waves = 3ot x 2mt)
//    -> unf read once total (-235 MB fabric vs R9/R11).
//  - C layout flips to col=b,row=o -> f32x4 contiguous output stores.
// unfold v1 / transpose / fallback unchanged (proven).

#define NB 32
#define NC 48
#define NO 48
#define NH 64
#define NW 64
#define NL 4096
#define NK 432
#define KPAD 448     // padded K in unf (14*32)
#define NM 1536      // NB*NO
#define UROW 14336   // NB*KPAD  (elems per l in unf)
#define XSP 456      // bf16 per LDS row in main (912 B, 2-way-conflict-free)
#define PITCH 456    // fallback kernels' LDS pitch (bf16)

typedef __bf16 bf16x8 __attribute__((ext_vector_type(8)));
typedef __bf16 bf16x4 __attribute__((ext_vector_type(4)));
typedef float f32x4 __attribute__((ext_vector_type(4)));

// ---------------- K1: unfold (v1)  x -> unf[l][b][kp448]  (bf16) ----------------
__global__ __launch_bounds__(256)
void lc2d_unfold(const float* __restrict__ x, __bf16* __restrict__ unf) {
    __shared__ float xl[NC * 3 * 66];   // row-padded [c*3+yy][66], col 0/65 = halo
    const int bid = blockIdx.x;
    const int h = bid >> 5;             // 0..63
    const int b = bid & 31;             // 0..31
    const int t = threadIdx.x;

#pragma unroll
    for (int it = 0; it < 36; ++it) {
        const int idx = t + it * 256;
        const int row = idx >> 6;       // c*3+yy, 0..143
        const int w = idx & 63;
        const int c = row / 3, yy = row - c * 3;
        const int y = h + yy - 1;
        float v = 0.0f;
        if ((unsigned)y < (unsigned)NH)
            v = x[(((size_t)(b * NC + c)) * NH + y) * NW + w];
        xl[row * 66 + 1 + w] = v;
    }
    if (t < 144) { xl[t * 66] = 0.0f; xl[t * 66 + 65] = 0.0f; }
    __syncthreads();

    __bf16* dst = unf + ((size_t)h * 64 * NB + b) * KPAD;
#pragma unroll
    for (int it = 0; it < 14; ++it) {
        const int idx = t + it * 256;   // 0..3583
        const int w = idx / 56, kc = idx - w * 56;
        bf16x8 val = {};
        if (kc < 54) {                  // kc 54,55 are K-pad -> zeros
#pragma unroll
            for (int j = 0; j < 8; ++j) {
                const int kp = kc * 8 + j;
                const int c = kp / 9, r9 = kp - c * 9;
                const int di = r9 / 3, dj = r9 - di * 3;
                val[j] = (__bf16)xl[(c * 3 + di) * 66 + w + dj];
            }
        }
        *(bf16x8*)(dst + (size_t)w * UROW + kc * 8) = val;
    }
}

// ---------------- K2: main v8  operand-swapped, weights global->reg ----------------
__global__ __launch_bounds__(384, 3)
void lc2d_main8(const __bf16* __restrict__ unf, const float* __restrict__ wgt,
                const float* __restrict__ bias, float* __restrict__ out_t) {
    __shared__ __bf16 xs[64 * XSP];     // 2l x 32b rows x 456 = 58368 B -> 2 blocks/CU

    const int t = threadIdx.x;
    const int bid = blockIdx.x;
    // XCD-chunked swizzle: 2048 blocks, 256 per XCD, consecutive l0 per XCD
    const int u = (bid & 7) * 256 + (bid >> 3);
    const int l0 = u * 2;

    // ---- stage unf tile ONCE: 64 rows (l_in*32+b) x 448 k, contiguous reads,
    // conflict-free writes (consecutive lanes -> consecutive chunks)
    const __bf16* src0 = unf + (size_t)l0 * UROW;
#pragma unroll
    for (int it = 0; it < 10; ++it) {
        const int idx = t + it * 384;        // 3584 chunks total
        if (idx < 3584) {
            const int row = idx / 56, kc = idx - row * 56;
            bf16x8 v = *(const bf16x8*)(src0 + (size_t)row * KPAD + kc * 8);
            *(bf16x8*)&xs[row * XSP + kc * 8] = v;
        }
    }
    __syncthreads();

    const int lane = t & 63, wid = t >> 6;   // 6 waves
    const int mt = wid & 1, ot = wid >> 1;   // b-half, o-third
    const int rrow = lane & 15, g = lane >> 4;
    const int o = ot * 16 + rrow;            // A-side row (o) for this lane

    // bias for this lane's 4 output o-values: o_out = ot*16 + g*4 + r
    const float4 bsv = *(const float4*)(bias + ot * 16 + g * 4);

#pragma unroll
    for (int l_in = 0; l_in < 2; ++l_in) {
        const int l = l0 + l_in;
        const float* wp = wgt + ((size_t)o * NL + l) * NK + g * 8;
        const __bf16* pb = &xs[(l_in * 32 + mt * 16 + rrow) * XSP + g * 8];

        f32x4 acc = {0.f, 0.f, 0.f, 0.f};
#pragma unroll
        for (int ks = 0; ks < 14; ++ks) {
            f32x4 a0 = {0.f, 0.f, 0.f, 0.f}, a1 = {0.f, 0.f, 0.f, 0.f};
            if (ks < 13 || g < 2) {          // ks13,g>=2: k>=432 (pad; also OOB guard)
                a0 = *(const f32x4*)(wp + ks * 32);
                a1 = *(const f32x4*)(wp + ks * 32 + 4);
            }
            bf16x8 af;
            af[0] = (__bf16)a0.x; af[1] = (__bf16)a0.y; af[2] = (__bf16)a0.z; af[3] = (__bf16)a0.w;
            af[4] = (__bf16)a1.x; af[5] = (__bf16)a1.y; af[6] = (__bf16)a1.z; af[7] = (__bf16)a1.w;
            bf16x8 bv = *(const bf16x8*)(pb + ks * 32);
            acc = __builtin_amdgcn_mfma_f32_16x16x32_bf16(af, bv, acc, 0, 0, 0);
        }

        // C layout: col(lane&15)=b, row((lane>>4)*4+r)=o_local -> f32x4 store
        const int b = mt * 16 + rrow;
        f32x4 res;
        res[0] = acc[0] + bsv.x; res[1] = acc[1] + bsv.y;
        res[2] = acc[2] + bsv.z; res[3] = acc[3] + bsv.w;
        *(f32x4*)(out_t + (size_t)l * NM + b * NO + ot * 16 + g * 4) = res;
    }
}

// ---------------- K3: transpose  out[m][l] = out_t[l][m] ----------------
__global__ __launch_bounds__(256)
void lc2d_transpose(const float* __restrict__ src, float* __restrict__ dst) {
    __shared__ float tile[32][33];
    const int bid = blockIdx.x;
    const int mt = bid % (NM / 32), lt = bid / (NM / 32);
    const int m0 = mt * 32, l0 = lt * 32;
    const int tid = threadIdx.x;
    const int c = tid & 31, rq = tid >> 5;
#pragma unroll
    for (int p = 0; p < 4; ++p) {
        const int lr = p * 8 + rq;
        tile[lr][c] = src[(size_t)(l0 + lr) * NM + m0 + c];
    }
    __syncthreads();
#pragma unroll
    for (int p = 0; p < 4; ++p) {
        const int mr = p * 8 + rq;
        dst[(size_t)(m0 + mr) * NL + l0 + c] = tile[c][mr];
    }
}

// ---------------- fallback (R4): fused staging kernel ----------------
template <int MODE>   // 0 = direct scattered stores, 1 = transposed scratch
__global__ __launch_bounds__(384, 3)
void lc2d_fallback(const float* __restrict__ x, const float* __restrict__ wgt,
                   const float* __restrict__ bias, float* __restrict__ outp) {
    __shared__ __bf16 xs[NB * PITCH];
    __shared__ __bf16 ws[NO * PITCH];
    const int t = threadIdx.x;
    const int bid = blockIdx.x;
    const int l = (bid & 7) * 512 + (bid >> 3);
    const int h = l >> 6;
    const int w = l & 63;
    const float* wbase = wgt + (size_t)l * NK;
    float4 va[7], vb[6];
#pragma unroll
    for (int i = 0; i < 7; ++i) {
        const int gi = t + i * 384;
        const int row = gi / 108, c = gi - row * 108;
        va[i] = *(const float4*)(wbase + (size_t)row * (NL * NK) + c * 4);
    }
#pragma unroll
    for (int i = 0; i < 6; ++i) {
        const int gi = t + (7 + i) * 384;
        const int row = gi / 108, c = gi - row * 108;
        vb[i] = *(const float4*)(wbase + (size_t)row * (NL * NK) + c * 4);
    }
    float4 vt;
    if (t < 5184 - 13 * 384) {
        const int gi = t + 13 * 384;
        const int row = gi / 108, c = gi - row * 108;
        vt = *(const float4*)(wbase + (size_t)row * (NL * NK) + c * 4);
    }
    float xv[4][9];
#pragma unroll
    for (int it = 0; it < 4; ++it) {
        const int idx = t + it * 384;
        const int b = idx / NC, c = idx - b * NC;
        const float* xb = x + ((size_t)(b * NC + c)) * (NH * NW);
#pragma unroll
        for (int di = 0; di < 3; ++di) {
            const int y = h + di - 1;
            const bool yok = (unsigned)y < (unsigned)NH;
#pragma unroll
            for (int dj = 0; dj < 3; ++dj) {
                const int xc = w + dj - 1;
                xv[it][di * 3 + dj] =
                    (yok && (unsigned)xc < (unsigned)NW) ? xb[y * NW + xc] : 0.0f;
            }
        }
    }
    {
        bf16x8 z = {};
        if (t < 144) { const int r = t / 3, ch = t - r * 3; *(bf16x8*)&ws[r * PITCH + NK + ch * 8] = z; }
        else if (t < 240) { const int q = t - 144; const int r = q / 3, ch = q - r * 3; *(bf16x8*)&xs[r * PITCH + NK + ch * 8] = z; }
    }
#pragma unroll
    for (int i = 0; i < 7; ++i) {
        const int gi = t + i * 384;
        const int row = gi / 108, c = gi - row * 108;
        bf16x4 bv4; bv4[0] = (__bf16)va[i].x; bv4[1] = (__bf16)va[i].y;
        bv4[2] = (__bf16)va[i].z; bv4[3] = (__bf16)va[i].w;
        *(bf16x4*)&ws[row * PITCH + c * 4] = bv4;
    }
#pragma unroll
    for (int i = 0; i < 6; ++i) {
        const int gi = t + (7 + i) * 384;
        const int row = gi / 108, c = gi - row * 108;
        bf16x4 bv4; bv4[0] = (__bf16)vb[i].x; bv4[1] = (__bf16)vb[i].y;
        bv4[2] = (__bf16)vb[i].z; bv4[3] = (__bf16)vb[i].w;
        *(bf16x4*)&ws[row * PITCH + c * 4] = bv4;
    }
    if (t < 5184 - 13 * 384) {
        const int gi = t + 13 * 384;
        const int row = gi / 108, c = gi - row * 108;
        bf16x4 bv4; bv4[0] = (__bf16)vt.x; bv4[1] = (__bf16)vt.y;
        bv4[2] = (__bf16)vt.z; bv4[3] = (__bf16)vt.w;
        *(bf16x4*)&ws[row * PITCH + c * 4] = bv4;
    }
#pragma unroll
    for (int it = 0; it < 4; ++it) {
        const int idx = t + it * 384;
        const int b = idx / NC, c = idx - b * NC;
        __bf16* dst = &xs[b * PITCH + c * 9];
#pragma unroll
        for (int k9 = 0; k9 < 9; ++k9) dst[k9] = (__bf16)xv[it][k9];
    }
    __syncthreads();
    const int lane = t & 63, wid = t >> 6;
    const int mt = wid & 1, ot = wid >> 1;
    const int rrow = lane & 15, g = lane >> 4;
    const int o = ot * 16 + rrow;
    const __bf16* pa = &xs[(mt * 16 + rrow) * PITCH + g * 8];
    const __bf16* pb = &ws[o * PITCH + g * 8];
    f32x4 acc = {0.f, 0.f, 0.f, 0.f};
#pragma unroll
    for (int ks = 0; ks < 14; ++ks) {
        bf16x8 avv = *(const bf16x8*)(pa + ks * 32);
        bf16x8 bvv = *(const bf16x8*)(pb + ks * 32);
        acc = __builtin_amdgcn_mfma_f32_16x16x32_bf16(avv, bvv, acc, 0, 0, 0);
    }
    const float bsv = bias[o];
#pragma unroll
    for (int r = 0; r < 4; ++r) {
        const int b = mt * 16 + g * 4 + r;
        if (MODE == 1) outp[(size_t)l * NM + b * NO + o] = acc[r] + bsv;
        else           outp[((size_t)(b * NO + o)) * NL + l] = acc[r] + bsv;
    }
}

extern "C" void kernel_launch(void* const* d_in, const int* in_sizes, int n_in,
                              void* d_out, int out_size, void* d_ws, size_t ws_size,
                              hipStream_t stream) {
    const float* x    = (const float*)d_in[0];
    const float* wgt  = (const float*)d_in[1];
    const float* bias = (const float*)d_in[2];
    float* out = (float*)d_out;

    const size_t unf_bytes  = (size_t)NL * NB * KPAD * sizeof(__bf16);  // 117.4 MB
    const size_t outt_bytes = (size_t)NL * NM * sizeof(float);          // 25.2 MB

    if (ws_size >= unf_bytes + outt_bytes) {
        __bf16* unf = (__bf16*)d_ws;
        float* out_t = (float*)((char*)d_ws + unf_bytes);
        lc2d_unfold<<<dim3(NH * NB), dim3(256), 0, stream>>>(x, unf);
        lc2d_main8<<<dim3(NL / 2), dim3(384), 0, stream>>>(unf, wgt, bias, out_t);
        lc2d_transpose<<<dim3((NM / 32) * (NL / 32)), dim3(256), 0, stream>>>(out_t, out);
    } else if (ws_size >= outt_bytes) {
        float* out_t = (float*)d_ws;
        lc2d_fallback<1><<<dim3(NL), dim3(384), 0, stream>>>(x, wgt, bias, out_t);
        lc2d_transpose<<<dim3((NM / 32) * (NL / 32)), dim3(256), 0, stream>>>(out_t, out);
    } else {
        lc2d_fallback<0><<<dim3(NL), dim3(384), 0, stream>>>(x, wgt, bias, out);
    }
}

// Round 13
// 179.534 us; speedup vs baseline: 1.1140x; 1.1140x over previous
//
#include <hip/hip_runtime.h>
#include <hip/hip_bf16.h>

// LocallyConnected2d: x(32,48,64,64) f32, weight(48,64,64,48,3,3) f32, bias(48) f32
// out(32,48,64,64) f32.  Per-location GEMM M=32(b) x N=48(o) x K=432, bf16 MFMA.
//
// R13 = R11 main (best, 177.6us) with the out_t+transpose stage REMOVED:
// main stores out[b][o][l] directly (4-B scattered, but XCD-chunked l-adjacency
// -> L2 write-merge; R1 measured 35MB WRITE for this pattern). Saves one
// launch, ~50MB scratch traffic, ~12us transpose time. Main compute/staging
// byte-identical to R11. unfold v1 unchanged.

#define NB 32
#define NC 48
#define NO 48
#define NH 64
#define NW 64
#define NL 4096
#define NK 432
#define KPAD 448     // padded K in unf (14*32)
#define NM 1536      // NB*NO
#define UROW 14336   // NB*KPAD  (elems per l in unf)
#define WSTRIDE 896  // f32 per o-row in main LDS (2l*432=864, padded to mult of 64)
#define PITCH 456    // fallback kernels' LDS pitch (bf16)

typedef __bf16 bf16x8 __attribute__((ext_vector_type(8)));
typedef __bf16 bf16x4 __attribute__((ext_vector_type(4)));
typedef float f32x4 __attribute__((ext_vector_type(4)));

// ---------------- K1: unfold (v1)  x -> unf[l][b][kp448]  (bf16) ----------------
__global__ __launch_bounds__(256)
void lc2d_unfold(const float* __restrict__ x, __bf16* __restrict__ unf) {
    __shared__ float xl[NC * 3 * 66];   // row-padded [c*3+yy][66], col 0/65 = halo
    const int bid = blockIdx.x;
    const int h = bid >> 5;             // 0..63
    const int b = bid & 31;             // 0..31
    const int t = threadIdx.x;

#pragma unroll
    for (int it = 0; it < 36; ++it) {
        const int idx = t + it * 256;
        const int row = idx >> 6;       // c*3+yy, 0..143
        const int w = idx & 63;
        const int c = row / 3, yy = row - c * 3;
        const int y = h + yy - 1;
        float v = 0.0f;
        if ((unsigned)y < (unsigned)NH)
            v = x[(((size_t)(b * NC + c)) * NH + y) * NW + w];
        xl[row * 66 + 1 + w] = v;
    }
    if (t < 144) { xl[t * 66] = 0.0f; xl[t * 66 + 65] = 0.0f; }
    __syncthreads();

    __bf16* dst = unf + ((size_t)h * 64 * NB + b) * KPAD;
#pragma unroll
    for (int it = 0; it < 14; ++it) {
        const int idx = t + it * 256;   // 0..3583
        const int w = idx / 56, kc = idx - w * 56;
        bf16x8 val = {};
        if (kc < 54) {                  // kc 54,55 are K-pad -> zeros
#pragma unroll
            for (int j = 0; j < 8; ++j) {
                const int kp = kc * 8 + j;
                const int c = kp / 9, r9 = kp - c * 9;
                const int di = r9 / 3, dj = r9 - di * 3;
                val[j] = (__bf16)xl[(c * 3 + di) * 66 + w + dj];
            }
        }
        *(bf16x8*)(dst + (size_t)w * UROW + kc * 8) = val;
    }
}

// ---------------- K2: main v9  (R11 structure, direct out stores) ----------------
__global__ __launch_bounds__(256, 2)
void lc2d_main9(const __bf16* __restrict__ unf, const float* __restrict__ wgt,
                const float* __restrict__ bias, float* __restrict__ out) {
    __shared__ float wsf[16 * WSTRIDE];   // 57344 B -> 2 blocks/CU

    const int t = threadIdx.x;
    const int bid = blockIdx.x;
    // XCD-chunked swizzle over u = (lgroup, ot): 6144 blocks, 768 per XCD.
    // ot cycles fastest -> 3 ot of same lg adjacent (unf L2 reuse), lg walks
    // sequentially per XCD (weight stream + out-line write-merge locality).
    const int u = (bid & 7) * 768 + (bid >> 3);
    const int lg = u / 3;                 // 0..2047
    const int ot = u - lg * 3;            // 0..2
    const int l0 = lg * 2;
    const int ob = ot * 16;

    const int lane = t & 63, wid = t >> 6;
    const int l_in = wid >> 1, mt = wid & 1;   // wave = (l 0..1) x (b-half)
    const int rrow = lane & 15, g = lane >> 4;
    const int o = ob + rrow;

    // ---- 1) weight staging: 16 o-rows x 224 granules (3456 B real + pad),
    // fire-and-forget glds.  LDS dest linear; SOURCE pre-swizzled so that
    // LDS granule rg of row holds SRC granule rg ^ ((row&7)<<1) (involution).
#pragma unroll
    for (int i = 0; i < 14; ++i) {
        const int s = i * 256 + t;            // 0..3583
        const int row = s / 224, rg = s - row * 224;
        int sg = rg ^ ((row & 7) << 1);       // granule-level swizzle
        if (sg >= 216) sg = 0;                // pad slots: clamped dup (finite)
        const float* src = wgt + ((size_t)(ob + row) * NL + l0) * NK + sg * 4;
        __builtin_amdgcn_global_load_lds((const void*)src, (void*)&wsf[s * 4], 16, 0, 0);
    }

    // ---- 2) A-fragments: dense bf16 reads from unf (14 KB window per wave)
    const __bf16* pa = unf + (size_t)(l0 + l_in) * UROW + (mt * 16 + rrow) * KPAD + g * 8;
    bf16x8 av[14];
#pragma unroll
    for (int ks = 0; ks < 14; ++ks) av[ks] = *(const bf16x8*)(pa + ks * 32);

    const float bsv = bias[o];

    __syncthreads();    // drains glds + av

    // ---- 3) 14 MFMA; B-frags: f32 LDS with read-side XOR, cvt to bf16
    const int sw = (rrow & 7) << 3;           // f32-index XOR
    f32x4 acc = {0.f, 0.f, 0.f, 0.f};
#pragma unroll
    for (int ks = 0; ks < 14; ++ks) {
        const int x = l_in * 432 + ks * 32 + g * 8;   // row-local f32 (low 3 bits 0)
        const int idx0 = rrow * WSTRIDE + (x ^ sw);
        f32x4 b0 = *(const f32x4*)&wsf[idx0];
        f32x4 b1 = *(const f32x4*)&wsf[idx0 + 4];
        bf16x8 bv;
        bv[0] = (__bf16)b0.x; bv[1] = (__bf16)b0.y; bv[2] = (__bf16)b0.z; bv[3] = (__bf16)b0.w;
        bv[4] = (__bf16)b1.x; bv[5] = (__bf16)b1.y; bv[6] = (__bf16)b1.z; bv[7] = (__bf16)b1.w;
        acc = __builtin_amdgcn_mfma_f32_16x16x32_bf16(av[ks], bv, acc, 0, 0, 0);
    }

    // ---- epilogue: C layout col(lane&15)=o, row((lane>>4)*4+r)=b.
    // DIRECT store to out[b][o][l]: 4-B scattered, L2 write-merged (XCD-chunked
    // l adjacency; R1 measured ~35MB WRITE for this pattern).
    const int l = l0 + l_in;
#pragma unroll
    for (int r = 0; r < 4; ++r) {
        const int b = mt * 16 + g * 4 + r;
        out[((size_t)(b * NO + o)) * NL + l] = acc[r] + bsv;
    }
}

// ---------------- K3: transpose (fallback path only) ----------------
__global__ __launch_bounds__(256)
void lc2d_transpose(const float* __restrict__ src, float* __restrict__ dst) {
    __shared__ float tile[32][33];
    const int bid = blockIdx.x;
    const int mt = bid % (NM / 32), lt = bid / (NM / 32);
    const int m0 = mt * 32, l0 = lt * 32;
    const int tid = threadIdx.x;
    const int c = tid & 31, rq = tid >> 5;
#pragma unroll
    for (int p = 0; p < 4; ++p) {
        const int lr = p * 8 + rq;
        tile[lr][c] = src[(size_t)(l0 + lr) * NM + m0 + c];
    }
    __syncthreads();
#pragma unroll
    for (int p = 0; p < 4; ++p) {
        const int mr = p * 8 + rq;
        dst[(size_t)(m0 + mr) * NL + l0 + c] = tile[c][mr];
    }
}

// ---------------- fallback (R4): fused staging kernel ----------------
template <int MODE>   // 0 = direct scattered stores, 1 = transposed scratch
__global__ __launch_bounds__(384, 3)
void lc2d_fallback(const float* __restrict__ x, const float* __restrict__ wgt,
                   const float* __restrict__ bias, float* __restrict__ outp) {
    __shared__ __bf16 xs[NB * PITCH];
    __shared__ __bf16 ws[NO * PITCH];
    const int t = threadIdx.x;
    const int bid = blockIdx.x;
    const int l = (bid & 7) * 512 + (bid >> 3);
    const int h = l >> 6;
    const int w = l & 63;
    const float* wbase = wgt + (size_t)l * NK;
    float4 va[7], vb[6];
#pragma unroll
    for (int i = 0; i < 7; ++i) {
        const int gi = t + i * 384;
        const int row = gi / 108, c = gi - row * 108;
        va[i] = *(const float4*)(wbase + (size_t)row * (NL * NK) + c * 4);
    }
#pragma unroll
    for (int i = 0; i < 6; ++i) {
        const int gi = t + (7 + i) * 384;
        const int row = gi / 108, c = gi - row * 108;
        vb[i] = *(const float4*)(wbase + (size_t)row * (NL * NK) + c * 4);
    }
    float4 vt;
    if (t < 5184 - 13 * 384) {
        const int gi = t + 13 * 384;
        const int row = gi / 108, c = gi - row * 108;
        vt = *(const float4*)(wbase + (size_t)row * (NL * NK) + c * 4);
    }
    float xv[4][9];
#pragma unroll
    for (int it = 0; it < 4; ++it) {
        const int idx = t + it * 384;
        const int b = idx / NC, c = idx - b * NC;
        const float* xb = x + ((size_t)(b * NC + c)) * (NH * NW);
#pragma unroll
        for (int di = 0; di < 3; ++di) {
            const int y = h + di - 1;
            const bool yok = (unsigned)y < (unsigned)NH;
#pragma unroll
            for (int dj = 0; dj < 3; ++dj) {
                const int xc = w + dj - 1;
                xv[it][di * 3 + dj] =
                    (yok && (unsigned)xc < (unsigned)NW) ? xb[y * NW + xc] : 0.0f;
            }
        }
    }
    {
        bf16x8 z = {};
        if (t < 144) { const int r = t / 3, ch = t - r * 3; *(bf16x8*)&ws[r * PITCH + NK + ch * 8] = z; }
        else if (t < 240) { const int q = t - 144; const int r = q / 3, ch = q - r * 3; *(bf16x8*)&xs[r * PITCH + NK + ch * 8] = z; }
    }
#pragma unroll
    for (int i = 0; i < 7; ++i) {
        const int gi = t + i * 384;
        const int row = gi / 108, c = gi - row * 108;
        bf16x4 bv4; bv4[0] = (__bf16)va[i].x; bv4[1] = (__bf16)va[i].y;
        bv4[2] = (__bf16)va[i].z; bv4[3] = (__bf16)va[i].w;
        *(bf16x4*)&ws[row * PITCH + c * 4] = bv4;
    }
#pragma unroll
    for (int i = 0; i < 6; ++i) {
        const int gi = t + (7 + i) * 384;
        const int row = gi / 108, c = gi - row * 108;
        bf16x4 bv4; bv4[0] = (__bf16)vb[i].x; bv4[1] = (__bf16)vb[i].y;
        bv4[2] = (__bf16)vb[i].z; bv4[3] = (__bf16)vb[i].w;
        *(bf16x4*)&ws[row * PITCH + c * 4] = bv4;
    }
    if (t < 5184 - 13 * 384) {
        const int gi = t + 13 * 384;
        const int row = gi / 108, c = gi - row * 108;
        bf16x4 bv4; bv4[0] = (__bf16)vt.x; bv4[1] = (__bf16)vt.y;
        bv4[2] = (__bf16)vt.z; bv4[3] = (__bf16)vt.w;
        *(bf16x4*)&ws[row * PITCH + c * 4] = bv4;
    }
#pragma unroll
    for (int it = 0; it < 4; ++it) {
        const int idx = t + it * 384;
        const int b = idx / NC, c = idx - b * NC;
        __bf16* dst = &xs[b * PITCH + c * 9];
#pragma unroll
        for (int k9 = 0; k9 < 9; ++k9) dst[k9] = (__bf16)xv[it][k9];
    }
    __syncthreads();
    const int lane = t & 63, wid = t >> 6;
    const int mt = wid & 1, ot = wid >> 1;
    const int rrow = lane & 15, g = lane >> 4;
    const int o = ot * 16 + rrow;
    const __bf16* pa = &xs[(mt * 16 + rrow) * PITCH + g * 8];
    const __bf16* pb = &ws[o * PITCH + g * 8];
    f32x4 acc = {0.f, 0.f, 0.f, 0.f};
#pragma unroll
    for (int ks = 0; ks < 14; ++ks) {
        bf16x8 avv = *(const bf16x8*)(pa + ks * 32);
        bf16x8 bvv = *(const bf16x8*)(pb + ks * 32);
        acc = __builtin_amdgcn_mfma_f32_16x16x32_bf16(avv, bvv, acc, 0, 0, 0);
    }
    const float bsv = bias[o];
#pragma unroll
    for (int r = 0; r < 4; ++r) {
        const int b = mt * 16 + g * 4 + r;
        if (MODE == 1) outp[(size_t)l * NM + b * NO + o] = acc[r] + bsv;
        else           outp[((size_t)(b * NO + o)) * NL + l] = acc[r] + bsv;
    }
}

extern "C" void kernel_launch(void* const* d_in, const int* in_sizes, int n_in,
                              void* d_out, int out_size, void* d_ws, size_t ws_size,
                              hipStream_t stream) {
    const float* x    = (const float*)d_in[0];
    const float* wgt  = (const float*)d_in[1];
    const float* bias = (const float*)d_in[2];
    float* out = (float*)d_out;

    const size_t unf_bytes  = (size_t)NL * NB * KPAD * sizeof(__bf16);  // 117.4 MB
    const size_t outt_bytes = (size_t)NL * NM * sizeof(float);          // 25.2 MB

    if (ws_size >= unf_bytes) {
        __bf16* unf = (__bf16*)d_ws;
        lc2d_unfold<<<dim3(NH * NB), dim3(256), 0, stream>>>(x, unf);
        lc2d_main9<<<dim3(NL / 2 * 3), dim3(256), 0, stream>>>(unf, wgt, bias, out);
    } else if (ws_size >= outt_bytes) {
        float* out_t = (float*)d_ws;
        lc2d_fallback<1><<<dim3(NL), dim3(384), 0, stream>>>(x, wgt, bias, out_t);
        lc2d_transpose<<<dim3((NM / 32) * (NL / 32)), dim3(256), 0, stream>>>(out_t, out);
    } else {
        lc2d_fallback<0><<<dim3(NL), dim3(384), 0, stream>>>(x, wgt, bias, out);
    }
}

// Round 14
// 152.972 us; speedup vs baseline: 1.3075x; 1.1736x over previous
//
#include <hip/hip_runtime.h>
#include <hip/hip_bf16.h>

// LocallyConnected2d: x(32,48,64,64) f32, weight(48,64,64,48,3,3) f32, bias(48) f32
// out(32,48,64,64) f32.  Per-location GEMM M=32(b) x N=48(o) x K=432, bf16 MFMA.
//
// R14 = R13 with ONE change: weight glds staged NON-TEMPORAL (aux=2 -> NT
// cpol bit). The 340MB zero-reuse weight stream no longer evicts unf (117MB)
// from L3, so main's A-fragment reads stay L3-hits. Loads: cpol is a pure
// caching hint, correctness-safe. Everything else byte-identical to R13.

#define NB 32
#define NC 48
#define NO 48
#define NH 64
#define NW 64
#define NL 4096
#define NK 432
#define KPAD 448     // padded K in unf (14*32)
#define NM 1536      // NB*NO
#define UROW 14336   // NB*KPAD  (elems per l in unf)
#define WSTRIDE 896  // f32 per o-row in main LDS (2l*432=864, padded to mult of 64)
#define PITCH 456    // fallback kernels' LDS pitch (bf16)

typedef __bf16 bf16x8 __attribute__((ext_vector_type(8)));
typedef __bf16 bf16x4 __attribute__((ext_vector_type(4)));
typedef float f32x4 __attribute__((ext_vector_type(4)));

// ---------------- K1: unfold (v1)  x -> unf[l][b][kp448]  (bf16) ----------------
__global__ __launch_bounds__(256)
void lc2d_unfold(const float* __restrict__ x, __bf16* __restrict__ unf) {
    __shared__ float xl[NC * 3 * 66];   // row-padded [c*3+yy][66], col 0/65 = halo
    const int bid = blockIdx.x;
    const int h = bid >> 5;             // 0..63
    const int b = bid & 31;             // 0..31
    const int t = threadIdx.x;

#pragma unroll
    for (int it = 0; it < 36; ++it) {
        const int idx = t + it * 256;
        const int row = idx >> 6;       // c*3+yy, 0..143
        const int w = idx & 63;
        const int c = row / 3, yy = row - c * 3;
        const int y = h + yy - 1;
        float v = 0.0f;
        if ((unsigned)y < (unsigned)NH)
            v = x[(((size_t)(b * NC + c)) * NH + y) * NW + w];
        xl[row * 66 + 1 + w] = v;
    }
    if (t < 144) { xl[t * 66] = 0.0f; xl[t * 66 + 65] = 0.0f; }
    __syncthreads();

    __bf16* dst = unf + ((size_t)h * 64 * NB + b) * KPAD;
#pragma unroll
    for (int it = 0; it < 14; ++it) {
        const int idx = t + it * 256;   // 0..3583
        const int w = idx / 56, kc = idx - w * 56;
        bf16x8 val = {};
        if (kc < 54) {                  // kc 54,55 are K-pad -> zeros
#pragma unroll
            for (int j = 0; j < 8; ++j) {
                const int kp = kc * 8 + j;
                const int c = kp / 9, r9 = kp - c * 9;
                const int di = r9 / 3, dj = r9 - di * 3;
                val[j] = (__bf16)xl[(c * 3 + di) * 66 + w + dj];
            }
        }
        *(bf16x8*)(dst + (size_t)w * UROW + kc * 8) = val;
    }
}

// ---------------- K2: main v10  (R13 structure, NT weight staging) ----------------
__global__ __launch_bounds__(256, 2)
void lc2d_main10(const __bf16* __restrict__ unf, const float* __restrict__ wgt,
                 const float* __restrict__ bias, float* __restrict__ out) {
    __shared__ float wsf[16 * WSTRIDE];   // 57344 B -> 2 blocks/CU

    const int t = threadIdx.x;
    const int bid = blockIdx.x;
    // XCD-chunked swizzle over u = (lgroup, ot): 6144 blocks, 768 per XCD.
    const int u = (bid & 7) * 768 + (bid >> 3);
    const int lg = u / 3;                 // 0..2047
    const int ot = u - lg * 3;            // 0..2
    const int l0 = lg * 2;
    const int ob = ot * 16;

    const int lane = t & 63, wid = t >> 6;
    const int l_in = wid >> 1, mt = wid & 1;   // wave = (l 0..1) x (b-half)
    const int rrow = lane & 15, g = lane >> 4;
    const int o = ob + rrow;

    // ---- 1) weight staging: 16 o-rows x 224 granules, fire-and-forget glds,
    // NON-TEMPORAL (aux=2): zero-reuse stream must not evict unf from L3.
    // LDS dest linear; SOURCE pre-swizzled (granule rg holds rg^((row&7)<<1)).
#pragma unroll
    for (int i = 0; i < 14; ++i) {
        const int s = i * 256 + t;            // 0..3583
        const int row = s / 224, rg = s - row * 224;
        int sg = rg ^ ((row & 7) << 1);       // granule-level swizzle
        if (sg >= 216) sg = 0;                // pad slots: clamped dup (finite)
        const float* src = wgt + ((size_t)(ob + row) * NL + l0) * NK + sg * 4;
        __builtin_amdgcn_global_load_lds((const void*)src, (void*)&wsf[s * 4], 16, 0, 2);
    }

    // ---- 2) A-fragments: dense bf16 reads from unf (14 KB window per wave)
    const __bf16* pa = unf + (size_t)(l0 + l_in) * UROW + (mt * 16 + rrow) * KPAD + g * 8;
    bf16x8 av[14];
#pragma unroll
    for (int ks = 0; ks < 14; ++ks) av[ks] = *(const bf16x8*)(pa + ks * 32);

    const float bsv = bias[o];

    __syncthreads();    // drains glds + av

    // ---- 3) 14 MFMA; B-frags: f32 LDS with read-side XOR, cvt to bf16
    const int sw = (rrow & 7) << 3;           // f32-index XOR
    f32x4 acc = {0.f, 0.f, 0.f, 0.f};
#pragma unroll
    for (int ks = 0; ks < 14; ++ks) {
        const int x = l_in * 432 + ks * 32 + g * 8;   // row-local f32 (low 3 bits 0)
        const int idx0 = rrow * WSTRIDE + (x ^ sw);
        f32x4 b0 = *(const f32x4*)&wsf[idx0];
        f32x4 b1 = *(const f32x4*)&wsf[idx0 + 4];
        bf16x8 bv;
        bv[0] = (__bf16)b0.x; bv[1] = (__bf16)b0.y; bv[2] = (__bf16)b0.z; bv[3] = (__bf16)b0.w;
        bv[4] = (__bf16)b1.x; bv[5] = (__bf16)b1.y; bv[6] = (__bf16)b1.z; bv[7] = (__bf16)b1.w;
        acc = __builtin_amdgcn_mfma_f32_16x16x32_bf16(av[ks], bv, acc, 0, 0, 0);
    }

    // ---- epilogue: C layout col(lane&15)=o, row((lane>>4)*4+r)=b.
    const int l = l0 + l_in;
#pragma unroll
    for (int r = 0; r < 4; ++r) {
        const int b = mt * 16 + g * 4 + r;
        out[((size_t)(b * NO + o)) * NL + l] = acc[r] + bsv;
    }
}

// ---------------- K3: transpose (fallback path only) ----------------
__global__ __launch_bounds__(256)
void lc2d_transpose(const float* __restrict__ src, float* __restrict__ dst) {
    __shared__ float tile[32][33];
    const int bid = blockIdx.x;
    const int mt = bid % (NM / 32), lt = bid / (NM / 32);
    const int m0 = mt * 32, l0 = lt * 32;
    const int tid = threadIdx.x;
    const int c = tid & 31, rq = tid >> 5;
#pragma unroll
    for (int p = 0; p < 4; ++p) {
        const int lr = p * 8 + rq;
        tile[lr][c] = src[(size_t)(l0 + lr) * NM + m0 + c];
    }
    __syncthreads();
#pragma unroll
    for (int p = 0; p < 4; ++p) {
        const int mr = p * 8 + rq;
        dst[(size_t)(m0 + mr) * NL + l0 + c] = tile[c][mr];
    }
}

// ---------------- fallback (R4): fused staging kernel ----------------
template <int MODE>   // 0 = direct scattered stores, 1 = transposed scratch
__global__ __launch_bounds__(384, 3)
void lc2d_fallback(const float* __restrict__ x, const float* __restrict__ wgt,
                   const float* __restrict__ bias, float* __restrict__ outp) {
    __shared__ __bf16 xs[NB * PITCH];
    __shared__ __bf16 ws[NO * PITCH];
    const int t = threadIdx.x;
    const int bid = blockIdx.x;
    const int l = (bid & 7) * 512 + (bid >> 3);
    const int h = l >> 6;
    const int w = l & 63;
    const float* wbase = wgt + (size_t)l * NK;
    float4 va[7], vb[6];
#pragma unroll
    for (int i = 0; i < 7; ++i) {
        const int gi = t + i * 384;
        const int row = gi / 108, c = gi - row * 108;
        va[i] = *(const float4*)(wbase + (size_t)row * (NL * NK) + c * 4);
    }
#pragma unroll
    for (int i = 0; i < 6; ++i) {
        const int gi = t + (7 + i) * 384;
        const int row = gi / 108, c = gi - row * 108;
        vb[i] = *(const float4*)(wbase + (size_t)row * (NL * NK) + c * 4);
    }
    float4 vt;
    if (t < 5184 - 13 * 384) {
        const int gi = t + 13 * 384;
        const int row = gi / 108, c = gi - row * 108;
        vt = *(const float4*)(wbase + (size_t)row * (NL * NK) + c * 4);
    }
    float xv[4][9];
#pragma unroll
    for (int it = 0; it < 4; ++it) {
        const int idx = t + it * 384;
        const int b = idx / NC, c = idx - b * NC;
        const float* xb = x + ((size_t)(b * NC + c)) * (NH * NW);
#pragma unroll
        for (int di = 0; di < 3; ++di) {
            const int y = h + di - 1;
            const bool yok = (unsigned)y < (unsigned)NH;
#pragma unroll
            for (int dj = 0; dj < 3; ++dj) {
                const int xc = w + dj - 1;
                xv[it][di * 3 + dj] =
                    (yok && (unsigned)xc < (unsigned)NW) ? xb[y * NW + xc] : 0.0f;
            }
        }
    }
    {
        bf16x8 z = {};
        if (t < 144) { const int r = t / 3, ch = t - r * 3; *(bf16x8*)&ws[r * PITCH + NK + ch * 8] = z; }
        else if (t < 240) { const int q = t - 144; const int r = q / 3, ch = q - r * 3; *(bf16x8*)&xs[r * PITCH + NK + ch * 8] = z; }
    }
#pragma unroll
    for (int i = 0; i < 7; ++i) {
        const int gi = t + i * 384;
        const int row = gi / 108, c = gi - row * 108;
        bf16x4 bv4; bv4[0] = (__bf16)va[i].x; bv4[1] = (__bf16)va[i].y;
        bv4[2] = (__bf16)va[i].z; bv4[3] = (__bf16)va[i].w;
        *(bf16x4*)&ws[row * PITCH + c * 4] = bv4;
    }
#pragma unroll
    for (int i = 0; i < 6; ++i) {
        const int gi = t + (7 + i) * 384;
        const int row = gi / 108, c = gi - row * 108;
        bf16x4 bv4; bv4[0] = (__bf16)vb[i].x; bv4[1] = (__bf16)vb[i].y;
        bv4[2] = (__bf16)vb[i].z; bv4[3] = (__bf16)vb[i].w;
        *(bf16x4*)&ws[row * PITCH + c * 4] = bv4;
    }
    if (t < 5184 - 13 * 384) {
        const int gi = t + 13 * 384;
        const int row = gi / 108, c = gi - row * 108;
        bf16x4 bv4; bv4[0] = (__bf16)vt.x; bv4[1] = (__bf16)vt.y;
        bv4[2] = (__bf16)vt.z; bv4[3] = (__bf16)vt.w;
        *(bf16x4*)&ws[row * PITCH + c * 4] = bv4;
    }
#pragma unroll
    for (int it = 0; it < 4; ++it) {
        const int idx = t + it * 384;
        const int b = idx / NC, c = idx - b * NC;
        __bf16* dst = &xs[b * PITCH + c * 9];
#pragma unroll
        for (int k9 = 0; k9 < 9; ++k9) dst[k9] = (__bf16)xv[it][k9];
    }
    __syncthreads();
    const int lane = t & 63, wid = t >> 6;
    const int mt = wid & 1, ot = wid >> 1;
    const int rrow = lane & 15, g = lane >> 4;
    const int o = ot * 16 + rrow;
    const __bf16* pa = &xs[(mt * 16 + rrow) * PITCH + g * 8];
    const __bf16* pb = &ws[o * PITCH + g * 8];
    f32x4 acc = {0.f, 0.f, 0.f, 0.f};
#pragma unroll
    for (int ks = 0; ks < 14; ++ks) {
        bf16x8 avv = *(const bf16x8*)(pa + ks * 32);
        bf16x8 bvv = *(const bf16x8*)(pb + ks * 32);
        acc = __builtin_amdgcn_mfma_f32_16x16x32_bf16(avv, bvv, acc, 0, 0, 0);
    }
    const float bsv = bias[o];
#pragma unroll
    for (int r = 0; r < 4; ++r) {
        const int b = mt * 16 + g * 4 + r;
        if (MODE == 1) outp[(size_t)l * NM + b * NO + o] = acc[r] + bsv;
        else           outp[((size_t)(b * NO + o)) * NL + l] = acc[r] + bsv;
    }
}

extern "C" void kernel_launch(void* const* d_in, const int* in_sizes, int n_in,
                              void* d_out, int out_size, void* d_ws, size_t ws_size,
                              hipStream_t stream) {
    const float* x    = (const float*)d_in[0];
    const float* wgt  = (const float*)d_in[1];
    const float* bias = (const float*)d_in[2];
    float* out = (float*)d_out;

    const size_t unf_bytes  = (size_t)NL * NB * KPAD * sizeof(__bf16);  // 117.4 MB
    const size_t outt_bytes = (size_t)NL * NM * sizeof(float);          // 25.2 MB

    if (ws_size >= unf_bytes) {
        __bf16* unf = (__bf16*)d_ws;
        lc2d_unfold<<<dim3(NH * NB), dim3(256), 0, stream>>>(x, unf);
        lc2d_main10<<<dim3(NL / 2 * 3), dim3(256), 0, stream>>>(unf, wgt, bias, out);
    } else if (ws_size >= outt_bytes) {
        float* out_t = (float*)d_ws;
        lc2d_fallback<1><<<dim3(NL), dim3(384), 0, stream>>>(x, wgt, bias, out_t);
        lc2d_transpose<<<dim3((NM / 32) * (NL / 32)), dim3(256), 0, stream>>>(out_t, out);
    } else {
        lc2d_fallback<0><<<dim3(NL), dim3(384), 0, stream>>>(x, wgt, bias, out);
    }
}

// Round 15
// 139.641 us; speedup vs baseline: 1.4323x; 1.0955x over previous
//
#include <hip/hip_runtime.h>
#include <hip/hip_bf16.h>

// LocallyConnected2d: x(32,48,64,64) f32, weight(48,64,64,48,3,3) f32, bias(48) f32
// out(32,48,64,64) f32.  Per-location GEMM M=32(b) x N=48(o) x K=432, bf16 MFMA.
//
// R15 = R14 (NT weight glds, 153us) with ONE structural change: block = one
// lg (2 l) looping ot=0..2 internally. A-fragments loaded ONCE per block and
// reused across the 3 weight stages -> unf fabric reads drop 352->117 MB
// (-235 MB, the last redundant bytes). Weight staging/stream/stores identical.

#define NB 32
#define NC 48
#define NO 48
#define NH 64
#define NW 64
#define NL 4096
#define NK 432
#define KPAD 448     // padded K in unf (14*32)
#define NM 1536      // NB*NO
#define UROW 14336   // NB*KPAD  (elems per l in unf)
#define WSTRIDE 896  // f32 per o-row in main LDS (2l*432=864, padded to mult of 64)
#define PITCH 456    // fallback kernels' LDS pitch (bf16)

typedef __bf16 bf16x8 __attribute__((ext_vector_type(8)));
typedef __bf16 bf16x4 __attribute__((ext_vector_type(4)));
typedef float f32x4 __attribute__((ext_vector_type(4)));

// ---------------- K1: unfold (v1)  x -> unf[l][b][kp448]  (bf16) ----------------
__global__ __launch_bounds__(256)
void lc2d_unfold(const float* __restrict__ x, __bf16* __restrict__ unf) {
    __shared__ float xl[NC * 3 * 66];   // row-padded [c*3+yy][66], col 0/65 = halo
    const int bid = blockIdx.x;
    const int h = bid >> 5;             // 0..63
    const int b = bid & 31;             // 0..31
    const int t = threadIdx.x;

#pragma unroll
    for (int it = 0; it < 36; ++it) {
        const int idx = t + it * 256;
        const int row = idx >> 6;       // c*3+yy, 0..143
        const int w = idx & 63;
        const int c = row / 3, yy = row - c * 3;
        const int y = h + yy - 1;
        float v = 0.0f;
        if ((unsigned)y < (unsigned)NH)
            v = x[(((size_t)(b * NC + c)) * NH + y) * NW + w];
        xl[row * 66 + 1 + w] = v;
    }
    if (t < 144) { xl[t * 66] = 0.0f; xl[t * 66 + 65] = 0.0f; }
    __syncthreads();

    __bf16* dst = unf + ((size_t)h * 64 * NB + b) * KPAD;
#pragma unroll
    for (int it = 0; it < 14; ++it) {
        const int idx = t + it * 256;   // 0..3583
        const int w = idx / 56, kc = idx - w * 56;
        bf16x8 val = {};
        if (kc < 54) {                  // kc 54,55 are K-pad -> zeros
#pragma unroll
            for (int j = 0; j < 8; ++j) {
                const int kp = kc * 8 + j;
                const int c = kp / 9, r9 = kp - c * 9;
                const int di = r9 / 3, dj = r9 - di * 3;
                val[j] = (__bf16)xl[(c * 3 + di) * 66 + w + dj];
            }
        }
        *(bf16x8*)(dst + (size_t)w * UROW + kc * 8) = val;
    }
}

// ---------------- K2: main v11  (ot-loop inside block, unf read once) ----------------
__global__ __launch_bounds__(256, 2)
void lc2d_main11(const __bf16* __restrict__ unf, const float* __restrict__ wgt,
                 const float* __restrict__ bias, float* __restrict__ out) {
    __shared__ float wsf[16 * WSTRIDE];   // 57344 B -> 2 blocks/CU

    const int t = threadIdx.x;
    const int bid = blockIdx.x;
    // XCD-chunked swizzle over lg: 2048 blocks, 256 per XCD, lg sequential.
    const int lg = (bid & 7) * 256 + (bid >> 3);   // 0..2047
    const int l0 = lg * 2;

    const int lane = t & 63, wid = t >> 6;
    const int l_in = wid >> 1, mt = wid & 1;   // wave = (l 0..1) x (b-half)
    const int rrow = lane & 15, g = lane >> 4;

    // ---- A-fragments: loaded ONCE, reused for all 3 ot (56 VGPR)
    const __bf16* pa = unf + (size_t)(l0 + l_in) * UROW + (mt * 16 + rrow) * KPAD + g * 8;
    bf16x8 av[14];
#pragma unroll
    for (int ks = 0; ks < 14; ++ks) av[ks] = *(const bf16x8*)(pa + ks * 32);

    const int l = l0 + l_in;
    const int sw = (rrow & 7) << 3;           // f32-index XOR for LDS reads

#pragma unroll
    for (int ot = 0; ot < 3; ++ot) {
        const int ob = ot * 16;

        // -- weight staging: 16 o-rows x 224 granules, glds NON-TEMPORAL
        //    (aux=2; zero-reuse stream must not evict unf). Source pre-swizzled:
        //    LDS granule rg of row holds SRC granule rg ^ ((row&7)<<1).
#pragma unroll
        for (int i = 0; i < 14; ++i) {
            const int s = i * 256 + t;            // 0..3583
            const int row = s / 224, rg = s - row * 224;
            int sg = rg ^ ((row & 7) << 1);       // granule-level swizzle
            if (sg >= 216) sg = 0;                // pad slots: clamped dup (finite)
            const float* src = wgt + ((size_t)(ob + row) * NL + l0) * NK + sg * 4;
            __builtin_amdgcn_global_load_lds((const void*)src, (void*)&wsf[s * 4], 16, 0, 2);
        }

        __syncthreads();    // drains glds (and av on first iter)

        // -- 14 MFMA; B-frags: f32 LDS with read-side XOR, cvt to bf16
        f32x4 acc = {0.f, 0.f, 0.f, 0.f};
#pragma unroll
        for (int ks = 0; ks < 14; ++ks) {
            const int xi = l_in * 432 + ks * 32 + g * 8;   // row-local f32
            const int idx0 = rrow * WSTRIDE + (xi ^ sw);
            f32x4 b0 = *(const f32x4*)&wsf[idx0];
            f32x4 b1 = *(const f32x4*)&wsf[idx0 + 4];
            bf16x8 bv;
            bv[0] = (__bf16)b0.x; bv[1] = (__bf16)b0.y; bv[2] = (__bf16)b0.z; bv[3] = (__bf16)b0.w;
            bv[4] = (__bf16)b1.x; bv[5] = (__bf16)b1.y; bv[6] = (__bf16)b1.z; bv[7] = (__bf16)b1.w;
            acc = __builtin_amdgcn_mfma_f32_16x16x32_bf16(av[ks], bv, acc, 0, 0, 0);
        }

        // -- epilogue: C layout col(lane&15)=o, row((lane>>4)*4+r)=b
        const int o = ob + rrow;
        const float bsv = bias[o];
#pragma unroll
        for (int r = 0; r < 4; ++r) {
            const int b = mt * 16 + g * 4 + r;
            out[((size_t)(b * NO + o)) * NL + l] = acc[r] + bsv;
        }

        if (ot < 2) __syncthreads();   // wsf reads done before next stage lands
    }
}

// ---------------- K3: transpose (fallback path only) ----------------
__global__ __launch_bounds__(256)
void lc2d_transpose(const float* __restrict__ src, float* __restrict__ dst) {
    __shared__ float tile[32][33];
    const int bid = blockIdx.x;
    const int mt = bid % (NM / 32), lt = bid / (NM / 32);
    const int m0 = mt * 32, l0 = lt * 32;
    const int tid = threadIdx.x;
    const int c = tid & 31, rq = tid >> 5;
#pragma unroll
    for (int p = 0; p < 4; ++p) {
        const int lr = p * 8 + rq;
        tile[lr][c] = src[(size_t)(l0 + lr) * NM + m0 + c];
    }
    __syncthreads();
#pragma unroll
    for (int p = 0; p < 4; ++p) {
        const int mr = p * 8 + rq;
        dst[(size_t)(m0 + mr) * NL + l0 + c] = tile[c][mr];
    }
}

// ---------------- fallback (R4): fused staging kernel ----------------
template <int MODE>   // 0 = direct scattered stores, 1 = transposed scratch
__global__ __launch_bounds__(384, 3)
void lc2d_fallback(const float* __restrict__ x, const float* __restrict__ wgt,
                   const float* __restrict__ bias, float* __restrict__ outp) {
    __shared__ __bf16 xs[NB * PITCH];
    __shared__ __bf16 ws[NO * PITCH];
    const int t = threadIdx.x;
    const int bid = blockIdx.x;
    const int l = (bid & 7) * 512 + (bid >> 3);
    const int h = l >> 6;
    const int w = l & 63;
    const float* wbase = wgt + (size_t)l * NK;
    float4 va[7], vb[6];
#pragma unroll
    for (int i = 0; i < 7; ++i) {
        const int gi = t + i * 384;
        const int row = gi / 108, c = gi - row * 108;
        va[i] = *(const float4*)(wbase + (size_t)row * (NL * NK) + c * 4);
    }
#pragma unroll
    for (int i = 0; i < 6; ++i) {
        const int gi = t + (7 + i) * 384;
        const int row = gi / 108, c = gi - row * 108;
        vb[i] = *(const float4*)(wbase + (size_t)row * (NL * NK) + c * 4);
    }
    float4 vt;
    if (t < 5184 - 13 * 384) {
        const int gi = t + 13 * 384;
        const int row = gi / 108, c = gi - row * 108;
        vt = *(const float4*)(wbase + (size_t)row * (NL * NK) + c * 4);
    }
    float xv[4][9];
#pragma unroll
    for (int it = 0; it < 4; ++it) {
        const int idx = t + it * 384;
        const int b = idx / NC, c = idx - b * NC;
        const float* xb = x + ((size_t)(b * NC + c)) * (NH * NW);
#pragma unroll
        for (int di = 0; di < 3; ++di) {
            const int y = h + di - 1;
            const bool yok = (unsigned)y < (unsigned)NH;
#pragma unroll
            for (int dj = 0; dj < 3; ++dj) {
                const int xc = w + dj - 1;
                xv[it][di * 3 + dj] =
                    (yok && (unsigned)xc < (unsigned)NW) ? xb[y * NW + xc] : 0.0f;
            }
        }
    }
    {
        bf16x8 z = {};
        if (t < 144) { const int r = t / 3, ch = t - r * 3; *(bf16x8*)&ws[r * PITCH + NK + ch * 8] = z; }
        else if (t < 240) { const int q = t - 144; const int r = q / 3, ch = q - r * 3; *(bf16x8*)&xs[r * PITCH + NK + ch * 8] = z; }
    }
#pragma unroll
    for (int i = 0; i < 7; ++i) {
        const int gi = t + i * 384;
        const int row = gi / 108, c = gi - row * 108;
        bf16x4 bv4; bv4[0] = (__bf16)va[i].x; bv4[1] = (__bf16)va[i].y;
        bv4[2] = (__bf16)va[i].z; bv4[3] = (__bf16)va[i].w;
        *(bf16x4*)&ws[row * PITCH + c * 4] = bv4;
    }
#pragma unroll
    for (int i = 0; i < 6; ++i) {
        const int gi = t + (7 + i) * 384;
        const int row = gi / 108, c = gi - row * 108;
        bf16x4 bv4; bv4[0] = (__bf16)vb[i].x; bv4[1] = (__bf16)vb[i].y;
        bv4[2] = (__bf16)vb[i].z; bv4[3] = (__bf16)vb[i].w;
        *(bf16x4*)&ws[row * PITCH + c * 4] = bv4;
    }
    if (t < 5184 - 13 * 384) {
        const int gi = t + 13 * 384;
        const int row = gi / 108, c = gi - row * 108;
        bf16x4 bv4; bv4[0] = (__bf16)vt.x; bv4[1] = (__bf16)vt.y;
        bv4[2] = (__bf16)vt.z; bv4[3] = (__bf16)vt.w;
        *(bf16x4*)&ws[row * PITCH + c * 4] = bv4;
    }
#pragma unroll
    for (int it = 0; it < 4; ++it) {
        const int idx = t + it * 384;
        const int b = idx / NC, c = idx - b * NC;
        __bf16* dst = &xs[b * PITCH + c * 9];
#pragma unroll
        for (int k9 = 0; k9 < 9; ++k9) dst[k9] = (__bf16)xv[it][k9];
    }
    __syncthreads();
    const int lane = t & 63, wid = t >> 6;
    const int mt = wid & 1, ot = wid >> 1;
    const int rrow = lane & 15, g = lane >> 4;
    const int o = ot * 16 + rrow;
    const __bf16* pa = &xs[(mt * 16 + rrow) * PITCH + g * 8];
    const __bf16* pb = &ws[o * PITCH + g * 8];
    f32x4 acc = {0.f, 0.f, 0.f, 0.f};
#pragma unroll
    for (int ks = 0; ks < 14; ++ks) {
        bf16x8 avv = *(const bf16x8*)(pa + ks * 32);
        bf16x8 bvv = *(const bf16x8*)(pb + ks * 32);
        acc = __builtin_amdgcn_mfma_f32_16x16x32_bf16(avv, bvv, acc, 0, 0, 0);
    }
    const float bsv = bias[o];
#pragma unroll
    for (int r = 0; r < 4; ++r) {
        const int b = mt * 16 + g * 4 + r;
        if (MODE == 1) outp[(size_t)l * NM + b * NO + o] = acc[r] + bsv;
        else           outp[((size_t)(b * NO + o)) * NL + l] = acc[r] + bsv;
    }
}

extern "C" void kernel_launch(void* const* d_in, const int* in_sizes, int n_in,
                              void* d_out, int out_size, void* d_ws, size_t ws_size,
                              hipStream_t stream) {
    const float* x    = (const float*)d_in[0];
    const float* wgt  = (const float*)d_in[1];
    const float* bias = (const float*)d_in[2];
    float* out = (float*)d_out;

    const size_t unf_bytes  = (size_t)NL * NB * KPAD * sizeof(__bf16);  // 117.4 MB
    const size_t outt_bytes = (size_t)NL * NM * sizeof(float);          // 25.2 MB

    if (ws_size >= unf_bytes) {
        __bf16* unf = (__bf16*)d_ws;
        lc2d_unfold<<<dim3(NH * NB), dim3(256), 0, stream>>>(x, unf);
        lc2d_main11<<<dim3(NL / 2), dim3(256), 0, stream>>>(unf, wgt, bias, out);
    } else if (ws_size >= outt_bytes) {
        float* out_t = (float*)d_ws;
        lc2d_fallback<1><<<dim3(NL), dim3(384), 0, stream>>>(x, wgt, bias, out_t);
        lc2d_transpose<<<dim3((NM / 32) * (NL / 32)), dim3(256), 0, stream>>>(out_t, out);
    } else {
        lc2d_fallback<0><<<dim3(NL), dim3(384), 0, stream>>>(x, wgt, bias, out);
    }
}